// Round 1
// 560.327 us; speedup vs baseline: 1.2452x; 1.2452x over previous
//
#include <hip/hip_runtime.h>
#include <hip/hip_bf16.h>
#include <math.h>

#define B_ 4
#define H_ 256
#define W_ 256
#define C_ 128
#define HEADS_ 4
#define HD_ 32
#define WS_ 8
#define SHIFT_ 4
#define T_ 64
#define NW_ 1024
#define M_ (B_*NW_*T_)   /* 262144 tokens */

typedef float floatx4 __attribute__((ext_vector_type(4)));
typedef short bf16x8 __attribute__((ext_vector_type(8)));   // 8 bf16 in 4 VGPRs
typedef unsigned short ushort8v __attribute__((ext_vector_type(8)));

#define MFMA16(a,b,c) __builtin_amdgcn_mfma_f32_16x16x32_bf16(a,b,c,0,0,0)

__device__ __forceinline__ unsigned short f2b(float f){
    union { float f; unsigned int i; } c; c.f = f;
    unsigned int r = c.i + 0x7FFFu + ((c.i >> 16) & 1u);
    return (unsigned short)(r >> 16);
}
__device__ __forceinline__ int region_id(int x){ return (x < 248) ? 0 : ((x < 252) ? 1 : 2); }

__device__ __forceinline__ bf16x8 ldfrag(const unsigned short* p){
    return *(const bf16x8*)p;                       // ds_read_b128 / global_load_dwordx4
}
__device__ __forceinline__ bf16x8 ldfrag_strided(const unsigned short* p, int stride){
    ushort8v u;
    #pragma unroll
    for (int j = 0; j < 8; j++) u[j] = p[j*stride];
    return __builtin_bit_cast(bf16x8, u);
}
__device__ __forceinline__ floatx4 fzero(){ floatx4 v = {0.f,0.f,0.f,0.f}; return v; }

// ---------------- workspace layout (ushort offsets) ----------------
// n-major bf16 weights: Wt[n*K + k] = W[k][n]  (B-fragment = 16B contiguous)
#define WSO_QT   0          /* 128x128 */
#define WSO_KT   16384
#define WSO_VT   32768
#define WSO_PT   49152
#define WSO_W1T  65536      /* [512 n][128 k] */
#define WSO_W2T  131072     /* [128 n][512 k] */
#define WSO_BIAS 196608     /* float[4][64][64] pre-gathered rpb */
#define WS_BYTES_NEEDED (196608u*2u + 16384u*4u)   /* 458752 */

// K0: one-time weight convert/transpose + rel-pos-bias gather (~1 us)
__global__ __launch_bounds__(256) void prep_weights_kernel(
        const float* __restrict__ qw, const float* __restrict__ kw,
        const float* __restrict__ vw, const float* __restrict__ pw,
        const float* __restrict__ fc1, const float* __restrict__ fc2,
        const float* __restrict__ rpb, unsigned short* __restrict__ ws)
{
    int tid = blockIdx.x * 256 + threadIdx.x;
    int nt = gridDim.x * 256;
    for (int i = tid; i < 16384; i += nt) {
        int n = i >> 7, k = i & 127;
        ws[WSO_QT + i] = f2b(qw[k*128 + n]);
        ws[WSO_KT + i] = f2b(kw[k*128 + n]);
        ws[WSO_VT + i] = f2b(vw[k*128 + n]);
        ws[WSO_PT + i] = f2b(pw[k*128 + n]);
    }
    for (int i = tid; i < 65536; i += nt) {
        int n = i >> 7, k = i & 127;                 // i = n*128 + k
        ws[WSO_W1T + i] = f2b(fc1[(size_t)k*512 + n]);
    }
    for (int i = tid; i < 65536; i += nt) {
        int n = i >> 9, k = i & 511;                 // i = n*512 + k
        ws[WSO_W2T + i] = f2b(fc2[(size_t)k*128 + n]);
    }
    float* bt = (float*)(ws + WSO_BIAS);
    for (int i = tid; i < 16384; i += nt) {
        int h = i >> 12, q = (i >> 6) & 63, k = i & 63;
        int th = q >> 3, tw = q & 7, jh = k >> 3, jw = k & 7;
        bt[i] = rpb[((th - jh + 7)*15 + (tw - jw + 7))*HEADS_ + h];
    }
}

// C[64x128] = Xs[64x128] @ Wt^T-layout global bf16; wave wv owns n-cols [32wv,32wv+32).
// No barriers, no LDS weight staging: B-fragments stream from L2.
__device__ __forceinline__ void gemm64x128_g(
        const unsigned short (*Xs)[136], const unsigned short* __restrict__ Wt,
        int wv, int quad, int l15, floatx4 acc[4][2])
{
    #pragma unroll
    for (int c = 0; c < 4; c++) {
        bf16x8 bf0 = ldfrag(Wt + (size_t)(32*wv + l15)*128      + c*32 + quad*8);
        bf16x8 bf1 = ldfrag(Wt + (size_t)(32*wv + 16 + l15)*128 + c*32 + quad*8);
        #pragma unroll
        for (int m = 0; m < 4; m++) {
            bf16x8 af = ldfrag(&Xs[16*m + l15][c*32 + quad*8]);
            acc[m][0] = MFMA16(af, bf0, acc[m][0]);
            acc[m][1] = MFMA16(af, bf1, acc[m][1]);
        }
    }
}

// K1: LN1 + shift-gather + QKV + windowed attention + proj + unshift-scatter + residual.
// All LDS tiles are written and re-read by the SAME wave (own 32-col slices); DS ops
// within a wave are in-order, so only 4 cross-wave barriers remain.
__global__ __launch_bounds__(256) void swin_attn_kernel2(
        const float* __restrict__ hidden,
        const float* __restrict__ ln1_s, const float* __restrict__ ln1_b,
        const float* __restrict__ q_b, const float* __restrict__ k_b,
        const float* __restrict__ v_b, const float* __restrict__ p_b,
        const unsigned short* __restrict__ wsu,
        float* __restrict__ xres)
{
    __shared__ __align__(16) unsigned short Xs[T_][136];   // LN1-out -> Q -> attn-out
    __shared__ __align__(16) unsigned short Ks[T_][136];   // K tile; later P (waves 0,1)
    __shared__ __align__(16) unsigned short Vs[T_][134];   // V tile (strided B-operand)
    __shared__ __align__(16) unsigned short PhU[2][2560];  // P stage (waves 2,3)

    int tid = threadIdx.x;
    int wv = tid >> 6, lane = tid & 63;      // wv doubles as head id
    int quad = lane >> 4, l15 = lane & 15;
    int gw = blockIdx.x;
    int wi = gw & (NW_-1), b = gw >> 10;
    int hb = wi >> 5, wb = wi & 31;

    // ---- LN1 over gathered (rolled) tokens; wave wv handles 16 tokens ----
    for (int it = 0; it < 16; it++) {
        int t = wv*16 + it;
        int th = t >> 3, tw = t & 7;
        int h = (hb*8 + th + SHIFT_) & 255;
        int w = (wb*8 + tw + SHIFT_) & 255;
        size_t src = ((size_t)((b<<16) + (h<<8) + w)) * C_;
        float2 u = *(const float2*)(hidden + src + 2*lane);
        float x0 = u.x, x1 = u.y;
        float s = x0 + x1, ss = x0*x0 + x1*x1;
        #pragma unroll
        for (int m = 32; m > 0; m >>= 1) {
            s  += __shfl_xor(s,  m, 64);
            ss += __shfl_xor(ss, m, 64);
        }
        float mean = s * (1.0f/C_);
        float var  = ss * (1.0f/C_) - mean*mean;
        float rstd = rsqrtf(var + 1e-5f);
        int c0 = 2*lane;
        ushort2 o;
        o.x = f2b((x0 - mean) * rstd * ln1_s[c0]   + ln1_b[c0]);
        o.y = f2b((x1 - mean) * rstd * ln1_s[c0+1] + ln1_b[c0+1]);
        *(ushort2*)&Xs[t][c0] = o;
    }
    __syncthreads();                          // Xs (all rows) ready for A-reads

    // ---- K GEMM -> Ks (own cols) ----
    {
        floatx4 acc[4][2];
        #pragma unroll
        for (int m = 0; m < 4; m++) { acc[m][0] = fzero(); acc[m][1] = fzero(); }
        gemm64x128_g(Xs, wsu + WSO_KT, wv, quad, l15, acc);
        float kb0 = k_b[32*wv + l15], kb1 = k_b[32*wv + 16 + l15];
        #pragma unroll
        for (int m = 0; m < 4; m++)
            #pragma unroll
            for (int r = 0; r < 4; r++) {
                int q = 16*m + 4*quad + r;
                Ks[q][32*wv + l15]      = f2b(acc[m][0][r] + kb0);
                Ks[q][32*wv + 16 + l15] = f2b(acc[m][1][r] + kb1);
            }
    }
    // ---- V GEMM -> Vs (own cols) ----
    {
        floatx4 acc[4][2];
        #pragma unroll
        for (int m = 0; m < 4; m++) { acc[m][0] = fzero(); acc[m][1] = fzero(); }
        gemm64x128_g(Xs, wsu + WSO_VT, wv, quad, l15, acc);
        float vb0 = v_b[32*wv + l15], vb1 = v_b[32*wv + 16 + l15];
        #pragma unroll
        for (int m = 0; m < 4; m++)
            #pragma unroll
            for (int r = 0; r < 4; r++) {
                int q = 16*m + 4*quad + r;
                Vs[q][32*wv + l15]      = f2b(acc[m][0][r] + vb0);
                Vs[q][32*wv + 16 + l15] = f2b(acc[m][1][r] + vb1);
            }
    }
    // ---- Q GEMM -> regs ----
    floatx4 qacc[4][2];
    #pragma unroll
    for (int m = 0; m < 4; m++) { qacc[m][0] = fzero(); qacc[m][1] = fzero(); }
    gemm64x128_g(Xs, wsu + WSO_QT, wv, quad, l15, qacc);
    __syncthreads();                          // all waves' Xs A-reads done
    {   // Q (scaled) -> Xs own cols
        const float sc = 0.17677669529663687f;
        float qb0 = q_b[32*wv + l15], qb1 = q_b[32*wv + 16 + l15];
        #pragma unroll
        for (int m = 0; m < 4; m++)
            #pragma unroll
            for (int r = 0; r < 4; r++) {
                int q = 16*m + 4*quad + r;
                Xs[q][32*wv + l15]      = f2b((qacc[m][0][r] + qb0) * sc);
                Xs[q][32*wv + 16 + l15] = f2b((qacc[m][1][r] + qb1) * sc);
            }
    }

    // ---- S = Q K^T (wave = head), own-col LDS reads, 16 MFMAs ----
    floatx4 sacc[4][4];
    #pragma unroll
    for (int m = 0; m < 4; m++)
        #pragma unroll
        for (int n = 0; n < 4; n++) sacc[m][n] = fzero();
    {
        bf16x8 qf[4], kf[4];
        #pragma unroll
        for (int m = 0; m < 4; m++) qf[m] = ldfrag(&Xs[16*m + l15][32*wv + quad*8]);
        #pragma unroll
        for (int n = 0; n < 4; n++) kf[n] = ldfrag(&Ks[16*n + l15][32*wv + quad*8]);
        #pragma unroll
        for (int m = 0; m < 4; m++)
            #pragma unroll
            for (int n = 0; n < 4; n++) sacc[m][n] = MFMA16(qf[m], kf[n], sacc[m][n]);
    }
    __syncthreads();                          // all Ks/Xs S-reads done; Ph may reuse Ks

    // ---- bias (pre-gathered table in ws) + shift-mask + softmax ----
    {
        const float* bt = (const float*)(wsu + WSO_BIAS) + (wv << 12);
        int cidj_[4];
        #pragma unroll
        for (int n = 0; n < 4; n++) {
            int kt = 16*n + l15;
            cidj_[n] = region_id(hb*8 + (kt >> 3))*3 + region_id(wb*8 + (kt & 7));
        }
        #pragma unroll
        for (int m = 0; m < 4; m++)
            #pragma unroll
            for (int r = 0; r < 4; r++) {
                int q = 16*m + 4*quad + r;
                int cidi = region_id(hb*8 + (q >> 3))*3 + region_id(wb*8 + (q & 7));
                float v[4];
                #pragma unroll
                for (int n = 0; n < 4; n++) {
                    float d = sacc[m][n][r] + bt[q*64 + 16*n + l15];
                    if (cidi != cidj_[n]) d -= 100.f;
                    v[n] = d;
                }
                float mx = fmaxf(fmaxf(v[0],v[1]), fmaxf(v[2],v[3]));
                #pragma unroll
                for (int off = 1; off < 16; off <<= 1) mx = fmaxf(mx, __shfl_xor(mx, off, 64));
                float sum = 0.f;
                #pragma unroll
                for (int n = 0; n < 4; n++) { v[n] = __expf(v[n] - mx); sum += v[n]; }
                #pragma unroll
                for (int off = 1; off < 16; off <<= 1) sum += __shfl_xor(sum, off, 64);
                float inv = 1.0f / sum;
                #pragma unroll
                for (int n = 0; n < 4; n++) sacc[m][n][r] = v[n] * inv;
            }
    }

    // ---- PV: P staged per 32-kt block into wave-private LDS (no barriers) ----
    unsigned short* Ph = (wv < 2) ? (&Ks[0][0] + wv*2560) : &PhU[wv-2][0];
    floatx4 oacc[4][2];
    #pragma unroll
    for (int m = 0; m < 4; m++) { oacc[m][0] = fzero(); oacc[m][1] = fzero(); }
    for (int kb = 0; kb < 2; kb++) {
        #pragma unroll
        for (int m = 0; m < 4; m++)
            #pragma unroll
            for (int r = 0; r < 4; r++) {
                int q = 16*m + 4*quad + r;
                Ph[q*40 + l15]      = f2b(sacc[m][2*kb+0][r]);
                Ph[q*40 + 16 + l15] = f2b(sacc[m][2*kb+1][r]);
            }
        bf16x8 bf0 = ldfrag_strided(&Vs[kb*32 + quad*8][32*wv + l15],      134);
        bf16x8 bf1 = ldfrag_strided(&Vs[kb*32 + quad*8][32*wv + 16 + l15], 134);
        #pragma unroll
        for (int m = 0; m < 4; m++) {
            bf16x8 af = ldfrag(&Ph[(16*m + l15)*40 + quad*8]);
            oacc[m][0] = MFMA16(af, bf0, oacc[m][0]);
            oacc[m][1] = MFMA16(af, bf1, oacc[m][1]);
        }
    }
    // ---- attn-out -> Xs (own cols) ----
    #pragma unroll
    for (int m = 0; m < 4; m++)
        #pragma unroll
        for (int r = 0; r < 4; r++) {
            int q = 16*m + 4*quad + r;
            Xs[q][32*wv + l15]      = f2b(oacc[m][0][r]);
            Xs[q][32*wv + 16 + l15] = f2b(oacc[m][1][r]);
        }
    __syncthreads();                          // O-writes visible for full-width A-reads
    // ---- proj GEMM + unshift scatter + residual -> xres ----
    {
        floatx4 acc[4][2];
        #pragma unroll
        for (int m = 0; m < 4; m++) { acc[m][0] = fzero(); acc[m][1] = fzero(); }
        gemm64x128_g(Xs, wsu + WSO_PT, wv, quad, l15, acc);
        float pb0 = p_b[32*wv + l15], pb1 = p_b[32*wv + 16 + l15];
        #pragma unroll
        for (int m = 0; m < 4; m++)
            #pragma unroll
            for (int r = 0; r < 4; r++) {
                int t = 16*m + 4*quad + r;
                int th = t >> 3, tw = t & 7;
                int h = (hb*8 + th + SHIFT_) & 255;
                int w = (wb*8 + tw + SHIFT_) & 255;
                size_t dst = ((size_t)((b<<16) + (h<<8) + w)) * C_;
                int c0 = 32*wv + l15;
                xres[dst + c0]      = hidden[dst + c0]      + acc[m][0][r] + pb0;
                xres[dst + c0 + 16] = hidden[dst + c0 + 16] + acc[m][1][r] + pb1;
            }
    }
}

// K2: LN2 + MLP in-place. Weights stream from pre-converted bf16 ws (B-frags are
// wave-private: no LDS staging, no conversion, 2 barriers/chunk). LDS = 26.6 KB.
__global__ __launch_bounds__(256) void mlp_ln_kernel2(
        float* __restrict__ xio,
        const float* __restrict__ ln2_s, const float* __restrict__ ln2_b,
        const float* __restrict__ b1, const float* __restrict__ b2,
        const unsigned short* __restrict__ wsu)
{
    __shared__ __align__(16) unsigned short As[T_][136];  // LN2 out (A-operand)
    __shared__ __align__(16) unsigned short G[T_][72];    // gelu out (A-operand stage2)
    const unsigned short* W1t = wsu + WSO_W1T;
    const unsigned short* W2t = wsu + WSO_W2T;
    int tid = threadIdx.x, wv = tid >> 6, lane = tid & 63;
    int quad = lane >> 4, l15 = lane & 15;
    size_t row0 = (size_t)blockIdx.x * 64;

    // ---- LN2 ----
    for (int it = 0; it < 16; it++) {
        int t = wv*16 + it;
        const float* xp = xio + (row0 + t)*C_;
        float2 u = *(const float2*)(xp + 2*lane);
        float x0 = u.x, x1 = u.y;
        float s = x0 + x1, ss = x0*x0 + x1*x1;
        #pragma unroll
        for (int m = 32; m > 0; m >>= 1) {
            s  += __shfl_xor(s,  m, 64);
            ss += __shfl_xor(ss, m, 64);
        }
        float mean = s * (1.0f/C_);
        float var  = ss * (1.0f/C_) - mean*mean;
        float rstd = rsqrtf(var + 1e-5f);
        int c0 = 2*lane;
        ushort2 o;
        o.x = f2b((x0 - mean) * rstd * ln2_s[c0]   + ln2_b[c0]);
        o.y = f2b((x1 - mean) * rstd * ln2_s[c0+1] + ln2_b[c0+1]);
        *(ushort2*)&As[t][c0] = o;
    }
    __syncthreads();                          // As ready

    floatx4 acc2[4][2];
    #pragma unroll
    for (int m = 0; m < 4; m++) { acc2[m][0] = fzero(); acc2[m][1] = fzero(); }

    for (int ch = 0; ch < 8; ch++) {
        // stage1: wave owns 16 n-cols; C1[64][64ch] = As @ W1   (B from global)
        floatx4 a1[4];
        #pragma unroll
        for (int m = 0; m < 4; m++) a1[m] = fzero();
        #pragma unroll
        for (int kc = 0; kc < 4; kc++) {
            bf16x8 bfrag = ldfrag(W1t + (size_t)(ch*64 + 16*wv + l15)*128 + kc*32 + quad*8);
            #pragma unroll
            for (int m = 0; m < 4; m++) {
                bf16x8 af = ldfrag(&As[16*m + l15][kc*32 + quad*8]);
                a1[m] = MFMA16(af, bfrag, a1[m]);
            }
        }
        __syncthreads();                      // prev chunk's G readers done
        {   // bias + exact gelu -> G (own cols)
            int c_rel = 16*wv + l15;
            float bb = b1[ch*64 + c_rel];
            #pragma unroll
            for (int m = 0; m < 4; m++)
                #pragma unroll
                for (int r = 0; r < 4; r++) {
                    int q = 16*m + 4*quad + r;
                    float hh = a1[m][r] + bb;
                    float g = 0.5f * hh * (1.0f + erff(hh * 0.70710678118654752f));
                    G[q][c_rel] = f2b(g);
                }
        }
        __syncthreads();                      // G visible
        // stage2: wave owns 32 n-cols; C2[64][128] += G @ W2, K=64 (B from global)
        #pragma unroll
        for (int ki = 0; ki < 2; ki++) {
            bf16x8 bf0 = ldfrag(W2t + (size_t)(32*wv + l15)*512      + ch*64 + ki*32 + quad*8);
            bf16x8 bf1 = ldfrag(W2t + (size_t)(32*wv + 16 + l15)*512 + ch*64 + ki*32 + quad*8);
            #pragma unroll
            for (int m = 0; m < 4; m++) {
                bf16x8 af = ldfrag(&G[16*m + l15][ki*32 + quad*8]);
                acc2[m][0] = MFMA16(af, bf0, acc2[m][0]);
                acc2[m][1] = MFMA16(af, bf1, acc2[m][1]);
            }
        }
    }
    // ---- epilogue: + b2 + residual (same-thread RMW, in-place safe) ----
    {
        float bb0 = b2[32*wv + l15], bb1 = b2[32*wv + 16 + l15];
        #pragma unroll
        for (int m = 0; m < 4; m++)
            #pragma unroll
            for (int r = 0; r < 4; r++) {
                size_t rr = row0 + 16*m + 4*quad + r;
                int c0 = 32*wv + l15;
                xio[rr*C_ + c0]      += acc2[m][0][r] + bb0;
                xio[rr*C_ + c0 + 16] += acc2[m][1][r] + bb1;
            }
    }
}

/* ===================== fallback path (ws too small) ===================== */

__device__ __forceinline__ void gemm64x128(
        const unsigned short (*Xs)[136], unsigned short (*Wc)[132],
        const float* __restrict__ Wg, int tid, int wv, int quad, int l15,
        floatx4 acc[4][2])
{
    for (int c = 0; c < 4; c++) {
        __syncthreads();
        #pragma unroll
        for (int it = 0; it < 4; it++) {
            int idx = tid + it*256;
            int kk = idx >> 5;
            int n4 = (idx & 31) * 4;
            float4 v = *(const float4*)(Wg + (size_t)(c*32 + kk)*C_ + n4);
            ushort4 o; o.x=f2b(v.x); o.y=f2b(v.y); o.z=f2b(v.z); o.w=f2b(v.w);
            *(ushort4*)&Wc[kk][n4] = o;
        }
        __syncthreads();
        bf16x8 bf0 = ldfrag_strided(&Wc[quad*8][32*wv + l15],      132);
        bf16x8 bf1 = ldfrag_strided(&Wc[quad*8][32*wv + 16 + l15], 132);
        #pragma unroll
        for (int m = 0; m < 4; m++) {
            bf16x8 af = ldfrag(&Xs[16*m + l15][c*32 + quad*8]);
            acc[m][0] = MFMA16(af, bf0, acc[m][0]);
            acc[m][1] = MFMA16(af, bf1, acc[m][1]);
        }
    }
}

__global__ __launch_bounds__(256) void swin_attn_kernel(
        const float* __restrict__ hidden,
        const float* __restrict__ ln1_s, const float* __restrict__ ln1_b,
        const float* __restrict__ q_w, const float* __restrict__ q_b,
        const float* __restrict__ k_w, const float* __restrict__ k_b,
        const float* __restrict__ v_w, const float* __restrict__ v_b,
        const float* __restrict__ p_w, const float* __restrict__ p_b,
        const float* __restrict__ rpb,
        float* __restrict__ xres)
{
    __shared__ unsigned short Xs[T_][136];
    __shared__ unsigned short Ks[T_][136];
    __shared__ unsigned short Vs[T_][134];
    __shared__ __align__(16) unsigned char U[10240];

    unsigned short (*Wc)[132] = (unsigned short(*)[132])U;
    float* rpbf = (float*)U;

    int tid = threadIdx.x;
    int wv = tid >> 6, lane = tid & 63;
    int quad = lane >> 4, l15 = lane & 15;
    int gw = blockIdx.x;
    int wi = gw & (NW_-1), b = gw >> 10;
    int hb = wi >> 5, wb = wi & 31;

    for (int it = 0; it < 16; it++) {
        int t = wv*16 + it;
        int th = t >> 3, tw = t & 7;
        int h = (hb*8 + th + SHIFT_) & 255;
        int w = (wb*8 + tw + SHIFT_) & 255;
        size_t src = ((size_t)((b<<16) + (h<<8) + w)) * C_;
        float2 u = *(const float2*)(hidden + src + 2*lane);
        float x0 = u.x, x1 = u.y;
        float s = x0 + x1, ss = x0*x0 + x1*x1;
        #pragma unroll
        for (int m = 32; m > 0; m >>= 1) {
            s  += __shfl_xor(s,  m, 64);
            ss += __shfl_xor(ss, m, 64);
        }
        float mean = s * (1.0f/C_);
        float var  = ss * (1.0f/C_) - mean*mean;
        float rstd = rsqrtf(var + 1e-5f);
        int c0 = 2*lane;
        ushort2 o;
        o.x = f2b((x0 - mean) * rstd * ln1_s[c0]   + ln1_b[c0]);
        o.y = f2b((x1 - mean) * rstd * ln1_s[c0+1] + ln1_b[c0+1]);
        *(ushort2*)&Xs[t][c0] = o;
    }

    {
        floatx4 acc[4][2];
        #pragma unroll
        for (int m = 0; m < 4; m++) { acc[m][0] = fzero(); acc[m][1] = fzero(); }
        gemm64x128(Xs, Wc, k_w, tid, wv, quad, l15, acc);
        float kb0 = k_b[32*wv + l15], kb1 = k_b[32*wv + 16 + l15];
        #pragma unroll
        for (int m = 0; m < 4; m++)
            #pragma unroll
            for (int r = 0; r < 4; r++) {
                int q = 16*m + 4*quad + r;
                Ks[q][32*wv + l15]      = f2b(acc[m][0][r] + kb0);
                Ks[q][32*wv + 16 + l15] = f2b(acc[m][1][r] + kb1);
            }
    }
    {
        floatx4 acc[4][2];
        #pragma unroll
        for (int m = 0; m < 4; m++) { acc[m][0] = fzero(); acc[m][1] = fzero(); }
        gemm64x128(Xs, Wc, v_w, tid, wv, quad, l15, acc);
        float vb0 = v_b[32*wv + l15], vb1 = v_b[32*wv + 16 + l15];
        #pragma unroll
        for (int m = 0; m < 4; m++)
            #pragma unroll
            for (int r = 0; r < 4; r++) {
                int q = 16*m + 4*quad + r;
                Vs[q][32*wv + l15]      = f2b(acc[m][0][r] + vb0);
                Vs[q][32*wv + 16 + l15] = f2b(acc[m][1][r] + vb1);
            }
    }
    floatx4 qacc[4][2];
    #pragma unroll
    for (int m = 0; m < 4; m++) { qacc[m][0] = fzero(); qacc[m][1] = fzero(); }
    gemm64x128(Xs, Wc, q_w, tid, wv, quad, l15, qacc);
    __syncthreads();
    for (int i = tid; i < 225*HEADS_; i += 256) rpbf[i] = rpb[i];
    {
        const float sc = 0.17677669529663687f;
        float qb0 = q_b[32*wv + l15], qb1 = q_b[32*wv + 16 + l15];
        #pragma unroll
        for (int m = 0; m < 4; m++)
            #pragma unroll
            for (int r = 0; r < 4; r++) {
                int q = 16*m + 4*quad + r;
                Xs[q][32*wv + l15]      = f2b((qacc[m][0][r] + qb0) * sc);
                Xs[q][32*wv + 16 + l15] = f2b((qacc[m][1][r] + qb1) * sc);
            }
    }
    __syncthreads();

    floatx4 sacc[4][4];
    #pragma unroll
    for (int m = 0; m < 4; m++)
        #pragma unroll
        for (int n = 0; n < 4; n++) sacc[m][n] = fzero();
    {
        bf16x8 qf[4], kf[4];
        #pragma unroll
        for (int m = 0; m < 4; m++) qf[m] = ldfrag(&Xs[16*m + l15][32*wv + quad*8]);
        #pragma unroll
        for (int n = 0; n < 4; n++) kf[n] = ldfrag(&Ks[16*n + l15][32*wv + quad*8]);
        #pragma unroll
        for (int m = 0; m < 4; m++)
            #pragma unroll
            for (int n = 0; n < 4; n++) sacc[m][n] = MFMA16(qf[m], kf[n], sacc[m][n]);
    }
    {
        int jh_[4], jw_[4], cidj_[4];
        #pragma unroll
        for (int n = 0; n < 4; n++) {
            int kt = 16*n + l15;
            jh_[n] = kt >> 3; jw_[n] = kt & 7;
            cidj_[n] = region_id(hb*8 + jh_[n])*3 + region_id(wb*8 + jw_[n]);
        }
        #pragma unroll
        for (int m = 0; m < 4; m++)
            #pragma unroll
            for (int r = 0; r < 4; r++) {
                int q = 16*m + 4*quad + r;
                int th = q >> 3, twq = q & 7;
                int cidi = region_id(hb*8 + th)*3 + region_id(wb*8 + twq);
                float v[4];
                #pragma unroll
                for (int n = 0; n < 4; n++) {
                    float d = sacc[m][n][r];
                    d += rpbf[((th - jh_[n] + 7)*15 + (twq - jw_[n] + 7))*HEADS_ + wv];
                    if (cidi != cidj_[n]) d -= 100.f;
                    v[n] = d;
                }
                float mx = fmaxf(fmaxf(v[0],v[1]), fmaxf(v[2],v[3]));
                #pragma unroll
                for (int off = 1; off < 16; off <<= 1) mx = fmaxf(mx, __shfl_xor(mx, off, 64));
                float sum = 0.f;
                #pragma unroll
                for (int n = 0; n < 4; n++) { v[n] = __expf(v[n] - mx); sum += v[n]; }
                #pragma unroll
                for (int off = 1; off < 16; off <<= 1) sum += __shfl_xor(sum, off, 64);
                float inv = 1.0f / sum;
                #pragma unroll
                for (int n = 0; n < 4; n++) sacc[m][n][r] = v[n] * inv;
            }
    }
    __syncthreads();

    unsigned short* Ph = (wv < 2) ? (&Ks[0][0] + wv*2560)
                                  : ((unsigned short*)U + (wv-2)*2560);
    floatx4 oacc[4][2];
    #pragma unroll
    for (int m = 0; m < 4; m++) { oacc[m][0] = fzero(); oacc[m][1] = fzero(); }
    for (int kb = 0; kb < 2; kb++) {
        #pragma unroll
        for (int m = 0; m < 4; m++)
            #pragma unroll
            for (int r = 0; r < 4; r++) {
                int q = 16*m + 4*quad + r;
                Ph[q*40 + l15]      = f2b(sacc[m][2*kb+0][r]);
                Ph[q*40 + 16 + l15] = f2b(sacc[m][2*kb+1][r]);
            }
        __syncthreads();
        bf16x8 bf0 = ldfrag_strided(&Vs[kb*32 + quad*8][32*wv + l15],      134);
        bf16x8 bf1 = ldfrag_strided(&Vs[kb*32 + quad*8][32*wv + 16 + l15], 134);
        #pragma unroll
        for (int m = 0; m < 4; m++) {
            bf16x8 af = ldfrag(&Ph[(16*m + l15)*40 + quad*8]);
            oacc[m][0] = MFMA16(af, bf0, oacc[m][0]);
            oacc[m][1] = MFMA16(af, bf1, oacc[m][1]);
        }
        __syncthreads();
    }
    #pragma unroll
    for (int m = 0; m < 4; m++)
        #pragma unroll
        for (int r = 0; r < 4; r++) {
            int q = 16*m + 4*quad + r;
            Xs[q][32*wv + l15]      = f2b(oacc[m][0][r]);
            Xs[q][32*wv + 16 + l15] = f2b(oacc[m][1][r]);
        }
    {
        floatx4 acc[4][2];
        #pragma unroll
        for (int m = 0; m < 4; m++) { acc[m][0] = fzero(); acc[m][1] = fzero(); }
        gemm64x128(Xs, Wc, p_w, tid, wv, quad, l15, acc);
        float pb0 = p_b[32*wv + l15], pb1 = p_b[32*wv + 16 + l15];
        #pragma unroll
        for (int m = 0; m < 4; m++)
            #pragma unroll
            for (int r = 0; r < 4; r++) {
                int t = 16*m + 4*quad + r;
                int th = t >> 3, tw = t & 7;
                int h = (hb*8 + th + SHIFT_) & 255;
                int w = (wb*8 + tw + SHIFT_) & 255;
                size_t dst = ((size_t)((b<<16) + (h<<8) + w)) * C_;
                int c0 = 32*wv + l15;
                xres[dst + c0]      = hidden[dst + c0]      + acc[m][0][r] + pb0;
                xres[dst + c0 + 16] = hidden[dst + c0 + 16] + acc[m][1][r] + pb1;
            }
    }
}

__global__ __launch_bounds__(256) void mlp_ln_kernel(
        float* __restrict__ xio,
        const float* __restrict__ ln2_s, const float* __restrict__ ln2_b,
        const float* __restrict__ W1, const float* __restrict__ b1,
        const float* __restrict__ W2, const float* __restrict__ b2)
{
    __shared__ unsigned short As[T_][136];
    __shared__ unsigned short G[T_][72];
    __shared__ unsigned short W1c[C_][68];
    __shared__ unsigned short W2c[T_][132];
    int tid = threadIdx.x, wv = tid >> 6, lane = tid & 63;
    int quad = lane >> 4, l15 = lane & 15;
    size_t row0 = (size_t)blockIdx.x * 64;

    for (int it = 0; it < 16; it++) {
        int t = wv*16 + it;
        const float* xp = xio + (row0 + t)*C_;
        float2 u = *(const float2*)(xp + 2*lane);
        float x0 = u.x, x1 = u.y;
        float s = x0 + x1, ss = x0*x0 + x1*x1;
        #pragma unroll
        for (int m = 32; m > 0; m >>= 1) {
            s  += __shfl_xor(s,  m, 64);
            ss += __shfl_xor(ss, m, 64);
        }
        float mean = s * (1.0f/C_);
        float var  = ss * (1.0f/C_) - mean*mean;
        float rstd = rsqrtf(var + 1e-5f);
        int c0 = 2*lane;
        ushort2 o;
        o.x = f2b((x0 - mean) * rstd * ln2_s[c0]   + ln2_b[c0]);
        o.y = f2b((x1 - mean) * rstd * ln2_s[c0+1] + ln2_b[c0+1]);
        *(ushort2*)&As[t][c0] = o;
    }

    floatx4 acc2[4][2];
    #pragma unroll
    for (int m = 0; m < 4; m++) { acc2[m][0] = fzero(); acc2[m][1] = fzero(); }

    for (int ch = 0; ch < 8; ch++) {
        __syncthreads();
        #pragma unroll
        for (int it = 0; it < 8; it++) {
            int idx = tid + it*256;
            int k = idx >> 4, n4 = (idx & 15) * 4;
            float4 v = *(const float4*)(W1 + (size_t)k*512 + ch*64 + n4);
            ushort4 o; o.x=f2b(v.x); o.y=f2b(v.y); o.z=f2b(v.z); o.w=f2b(v.w);
            *(ushort4*)&W1c[k][n4] = o;
        }
        #pragma unroll
        for (int it = 0; it < 8; it++) {
            int idx = tid + it*256;
            int k = idx >> 5, n4 = (idx & 31) * 4;
            float4 v = *(const float4*)(W2 + (size_t)(ch*64 + k)*C_ + n4);
            ushort4 o; o.x=f2b(v.x); o.y=f2b(v.y); o.z=f2b(v.z); o.w=f2b(v.w);
            *(ushort4*)&W2c[k][n4] = o;
        }
        __syncthreads();
        floatx4 a1[4];
        #pragma unroll
        for (int m = 0; m < 4; m++) a1[m] = fzero();
        #pragma unroll
        for (int kc = 0; kc < 4; kc++) {
            bf16x8 bfrag = ldfrag_strided(&W1c[kc*32 + quad*8][16*wv + l15], 68);
            #pragma unroll
            for (int m = 0; m < 4; m++) {
                bf16x8 af = ldfrag(&As[16*m + l15][kc*32 + quad*8]);
                a1[m] = MFMA16(af, bfrag, a1[m]);
            }
        }
        {
            int c_rel = 16*wv + l15;
            float bb = b1[ch*64 + c_rel];
            #pragma unroll
            for (int m = 0; m < 4; m++)
                #pragma unroll
                for (int r = 0; r < 4; r++) {
                    int q = 16*m + 4*quad + r;
                    float hh = a1[m][r] + bb;
                    float g = 0.5f * hh * (1.0f + erff(hh * 0.70710678118654752f));
                    G[q][c_rel] = f2b(g);
                }
        }
        __syncthreads();
        #pragma unroll
        for (int ki = 0; ki < 2; ki++) {
            bf16x8 bf0 = ldfrag_strided(&W2c[ki*32 + quad*8][32*wv + l15],      132);
            bf16x8 bf1 = ldfrag_strided(&W2c[ki*32 + quad*8][32*wv + 16 + l15], 132);
            #pragma unroll
            for (int m = 0; m < 4; m++) {
                bf16x8 af = ldfrag(&G[16*m + l15][ki*32 + quad*8]);
                acc2[m][0] = MFMA16(af, bf0, acc2[m][0]);
                acc2[m][1] = MFMA16(af, bf1, acc2[m][1]);
            }
        }
    }
    {
        float bb0 = b2[32*wv + l15], bb1 = b2[32*wv + 16 + l15];
        #pragma unroll
        for (int m = 0; m < 4; m++)
            #pragma unroll
            for (int r = 0; r < 4; r++) {
                size_t rr = row0 + 16*m + 4*quad + r;
                int c0 = 32*wv + l15;
                xio[rr*C_ + c0]      += acc2[m][0][r] + bb0;
                xio[rr*C_ + c0 + 16] += acc2[m][1][r] + bb1;
            }
    }
}

extern "C" void kernel_launch(void* const* d_in, const int* in_sizes, int n_in,
                              void* d_out, int out_size, void* d_ws, size_t ws_size,
                              hipStream_t stream) {
    (void)in_sizes; (void)n_in; (void)out_size;
    const float* hidden = (const float*)d_in[0];
    const float* ln1_s  = (const float*)d_in[1];
    const float* ln1_b  = (const float*)d_in[2];
    const float* q_w    = (const float*)d_in[3];
    const float* q_b    = (const float*)d_in[4];
    const float* k_w    = (const float*)d_in[5];
    const float* k_b    = (const float*)d_in[6];
    const float* v_w    = (const float*)d_in[7];
    const float* v_b    = (const float*)d_in[8];
    const float* p_w    = (const float*)d_in[9];
    const float* p_b    = (const float*)d_in[10];
    const float* rpb    = (const float*)d_in[11];
    const float* ln2_s  = (const float*)d_in[12];
    const float* ln2_b  = (const float*)d_in[13];
    const float* fc1_w  = (const float*)d_in[14];
    const float* fc1_b  = (const float*)d_in[15];
    const float* fc2_w  = (const float*)d_in[16];
    const float* fc2_b  = (const float*)d_in[17];
    float* outp = (float*)d_out;

    if (d_ws != nullptr && ws_size >= (size_t)WS_BYTES_NEEDED) {
        unsigned short* wsu = (unsigned short*)d_ws;
        prep_weights_kernel<<<64, 256, 0, stream>>>(q_w, k_w, v_w, p_w,
                fc1_w, fc2_w, rpb, wsu);
        swin_attn_kernel2<<<B_*NW_, 256, 0, stream>>>(hidden, ln1_s, ln1_b,
                q_b, k_b, v_b, p_b, wsu, outp);
        mlp_ln_kernel2<<<M_/64, 256, 0, stream>>>(outp, ln2_s, ln2_b,
                fc1_b, fc2_b, wsu);
    } else {
        swin_attn_kernel<<<B_*NW_, 256, 0, stream>>>(hidden, ln1_s, ln1_b,
                q_w, q_b, k_w, k_b, v_w, v_b, p_w, p_b, rpb, outp);
        mlp_ln_kernel<<<M_/64, 256, 0, stream>>>(outp, ln2_s, ln2_b,
                fc1_w, fc1_b, fc2_w, fc2_b);
    }
}